// Round 1
// baseline (18.102 us; speedup 1.0000x reference)
//
#include <hip/hip_runtime.h>
#include <hip/hip_bf16.h>

// Embedding gather: out[token, :] = weight[x[token], :]
// x: [B*S] int32 indices (4096), weight: [V, D] fp32 (32000 x 512),
// out: [B*S, D] fp32.
//
// D = 512 fp32 = 128 float4 per row. One float4 per thread, fully
// coalesced 16B/lane loads and stores.

__global__ __launch_bounds__(256) void emb_gather_kernel(
    const int* __restrict__ x,
    const float4* __restrict__ w4,      // weight viewed as [V][128] float4
    float4* __restrict__ out4,          // out viewed as [T][128] float4
    int total4)                         // T * 128
{
    int t = blockIdx.x * blockDim.x + threadIdx.x;
    if (t >= total4) return;
    int row = t >> 7;          // token index   (D4 = 128)
    int col = t & 127;         // float4 column within the row
    int idx = x[row];          // broadcast within wave; L1-cached across waves
    out4[t] = w4[(size_t)idx * 128 + col];
}

extern "C" void kernel_launch(void* const* d_in, const int* in_sizes, int n_in,
                              void* d_out, int out_size, void* d_ws, size_t ws_size,
                              hipStream_t stream) {
    const int*   x = (const int*)d_in[0];     // [B*S] = 4096 indices
    const float* w = (const float*)d_in[1];   // [32000 * 512] fp32

    int n_tokens = in_sizes[0];               // 4096
    int total4   = n_tokens * 128;            // one float4 per thread

    int block = 256;
    int grid  = (total4 + block - 1) / block; // 2048 blocks

    emb_gather_kernel<<<grid, block, 0, stream>>>(
        x,
        reinterpret_cast<const float4*>(w),
        reinterpret_cast<float4*>(d_out),
        total4);
}

// Round 2
// 10.658 us; speedup vs baseline: 1.6984x; 1.6984x over previous
//
#include <hip/hip_runtime.h>
#include <hip/hip_bf16.h>

// Embedding gather: out[token, :] = weight[x[token], :]
// x: [4096] int32, weight: [32000, 512] fp32, out: [4096, 512] fp32.
//
// ILP-4 variant: each thread owns 4 float4 of one row (cols c, c+32, c+64,
// c+96 -> 512B-apart immediate offsets), so a wave issues 4 independent
// gather loads before its first waitcnt. Non-temporal stores keep the
// write stream out of L2/L3 (out is never re-read; weight stays cached).

typedef float f32x4 __attribute__((ext_vector_type(4)));

__global__ __launch_bounds__(256) void emb_gather_ilp4(
    const int* __restrict__ x,
    const f32x4* __restrict__ w4,      // weight as [V][128] float4
    f32x4* __restrict__ out4,          // out as [T][128] float4
    int nthreads)                      // T * 32  (4 float4 per thread)
{
    int t = blockIdx.x * blockDim.x + threadIdx.x;
    if (t >= nthreads) return;

    int row = t >> 5;                  // token index (32 threads per row)
    int col = t & 31;                  // base float4 column

    int idx = x[row];                  // tiny table, L2-hot after first wave

    const f32x4* __restrict__ src = w4 + (size_t)idx * 128 + col;
    f32x4* __restrict__ dst       = out4 + (size_t)row * 128 + col;

    // 4 independent loads: one vaddr + 3 immediate offsets (512/1024/1536 B)
    f32x4 a = src[0];
    f32x4 b = src[32];
    f32x4 c = src[64];
    f32x4 d = src[96];

    __builtin_nontemporal_store(a, dst + 0);
    __builtin_nontemporal_store(b, dst + 32);
    __builtin_nontemporal_store(c, dst + 64);
    __builtin_nontemporal_store(d, dst + 96);
}

extern "C" void kernel_launch(void* const* d_in, const int* in_sizes, int n_in,
                              void* d_out, int out_size, void* d_ws, size_t ws_size,
                              hipStream_t stream) {
    const int*   x = (const int*)d_in[0];     // [4096] indices
    const float* w = (const float*)d_in[1];   // [32000 * 512] fp32

    int n_tokens = in_sizes[0];               // 4096
    int nthreads = n_tokens * 32;             // 131072 threads, 4 float4 each

    int block = 256;
    int grid  = (nthreads + block - 1) / block; // 512 blocks

    emb_gather_ilp4<<<grid, block, 0, stream>>>(
        x,
        reinterpret_cast<const f32x4*>(w),
        reinterpret_cast<f32x4*>(d_out),
        nthreads);
}